// Round 1
// baseline (194.250 us; speedup 1.0000x reference)
//
#include <hip/hip_runtime.h>

typedef __attribute__((ext_vector_type(8))) short bf16x8;
typedef __attribute__((ext_vector_type(4))) float f32x4;
typedef __attribute__((ext_vector_type(4))) short short4v;

#define B_  2
#define T_  2048
#define D_  1024
#define H_  16
#define HD_ 64

__device__ inline short f2bf(float f){
  unsigned u = __builtin_bit_cast(unsigned, f);
  u += 0x7fff + ((u >> 16) & 1);          // round-to-nearest-even
  return (short)(u >> 16);
}

__device__ inline void gl2lds16(const void* g, void* l){
  __builtin_amdgcn_global_load_lds(
      (const __attribute__((address_space(1))) unsigned int*)g,
      (__attribute__((address_space(3))) unsigned int*)l, 16, 0, 0);
}

// ---------------- elementwise f32 -> bf16 ----------------
__global__ __launch_bounds__(256) void convert_f32_bf16(
    const float* __restrict__ in, short* __restrict__ out){
  int i = (blockIdx.x * 256 + threadIdx.x) * 4;
  float4 v = *(const float4*)(in + i);
  short4v o;
  o[0] = f2bf(v.x); o[1] = f2bf(v.y); o[2] = f2bf(v.z); o[3] = f2bf(v.w);
  *(short4v*)(out + i) = o;
}

// ---------------- f32 [R][C] -> bf16 [C][R] ----------------
__global__ __launch_bounds__(256) void transpose_f32_bf16(
    const float* __restrict__ in, short* __restrict__ out, int R, int C){
  __shared__ float tile[32][33];
  int tx = threadIdx.x & 31, ty0 = threadIdx.x >> 5;
  int bx = blockIdx.x << 5, by = blockIdx.y << 5;
#pragma unroll
  for (int i = 0; i < 4; i++){
    int ty = ty0 + i * 8;
    tile[ty][tx] = in[(by + ty) * C + bx + tx];
  }
  __syncthreads();
#pragma unroll
  for (int i = 0; i < 4; i++){
    int ty = ty0 + i * 8;
    out[(bx + ty) * R + by + tx] = f2bf(tile[tx][ty]);
  }
}

// ---------------- GEMM: C = A[M][K] @ Bt[N][K]^T + bias ----------------
// EPI 0: QKV epilogue (scatter q,k,vT bf16).  EPI 1: f32 out.
#define BM 128
#define BN 128
#define BK 32

template<int N_, int K_, int EPI>
__global__ __launch_bounds__(256) void gemm_bt(
    const short* __restrict__ A, const short* __restrict__ Bt,
    const float* __restrict__ bias,
    short* __restrict__ q, short* __restrict__ kk, short* __restrict__ vT,
    float* __restrict__ outf){
  __shared__ short As[BM * BK];
  __shared__ short Bs[BN * BK];
  const int tid = threadIdx.x;
  const int lane = tid & 63, w = tid >> 6;
  const int wm = w >> 1, wn = w & 1;
  const int lr = lane & 15, lk = lane >> 4;
  const int brow = blockIdx.y * BM, bcol = blockIdx.x * BN;
  f32x4 acc[4][4] = {};
  const short* Ag = A  + brow * K_;
  const short* Bg = Bt + bcol * K_;

  for (int k0 = 0; k0 < K_; k0 += BK){
#pragma unroll
    for (int i = 0; i < 2; i++){
      int idx = i * 256 + tid;
      int row = idx >> 2, c8 = (idx & 3) * 8;   // 64B rows of 32 bf16
      gl2lds16(Ag + row * K_ + k0 + c8, (char*)As + idx * 16);
      gl2lds16(Bg + row * K_ + k0 + c8, (char*)Bs + idx * 16);
    }
    __syncthreads();
    bf16x8 a[4], b[4];
#pragma unroll
    for (int mf = 0; mf < 4; mf++)
      a[mf] = *(const bf16x8*)(As + (wm * 64 + mf * 16 + lr) * BK + lk * 8);
#pragma unroll
    for (int nf = 0; nf < 4; nf++)
      b[nf] = *(const bf16x8*)(Bs + (wn * 64 + nf * 16 + lr) * BK + lk * 8);
#pragma unroll
    for (int mf = 0; mf < 4; mf++)
#pragma unroll
      for (int nf = 0; nf < 4; nf++)
        acc[mf][nf] = __builtin_amdgcn_mfma_f32_16x16x32_bf16(a[mf], b[nf], acc[mf][nf], 0, 0, 0);
    __syncthreads();
  }

  if constexpr (EPI == 0){
    // C/D layout: col = lane&15, row = (lane>>4)*4 + r
#pragma unroll
    for (int nf = 0; nf < 4; nf++){
      int n = bcol + wn * 64 + nf * 16 + lr;
      float bv = bias[n];
      int sec = n >> 10, d = n & 1023, h = d >> 6, hd = d & 63;
#pragma unroll
      for (int mf = 0; mf < 4; mf++){
        int m0 = brow + wm * 64 + mf * 16 + lk * 4;
        int b = m0 >> 11, t0 = m0 & 2047;
        int bh = b * H_ + h;
        if (sec == 0){
#pragma unroll
          for (int r = 0; r < 4; r++)
            q[(bh * T_ + t0 + r) * HD_ + hd] = f2bf((acc[mf][nf][r] + bv) * 0.125f);
        } else if (sec == 1){
#pragma unroll
          for (int r = 0; r < 4; r++)
            kk[(bh * T_ + t0 + r) * HD_ + hd] = f2bf(acc[mf][nf][r] + bv);
        } else {
          float v0 = acc[mf][nf][0] + bv, v1 = acc[mf][nf][1] + bv;
          float v2 = acc[mf][nf][2] + bv, v3 = acc[mf][nf][3] + bv;
          unsigned lo = (unsigned)(unsigned short)f2bf(v0) | ((unsigned)(unsigned short)f2bf(v1) << 16);
          unsigned hi = (unsigned)(unsigned short)f2bf(v2) | ((unsigned)(unsigned short)f2bf(v3) << 16);
          uint2 pk; pk.x = lo; pk.y = hi;
          *(uint2*)(vT + (bh * HD_ + hd) * T_ + t0) = pk;   // v stored transposed [B,H,hd,T]
        }
      }
    }
  } else {
#pragma unroll
    for (int nf = 0; nf < 4; nf++){
      int n = bcol + wn * 64 + nf * 16 + lr;
      float bv = bias[n];
#pragma unroll
      for (int mf = 0; mf < 4; mf++){
        int m0 = brow + wm * 64 + mf * 16 + lk * 4;
#pragma unroll
        for (int r = 0; r < 4; r++)
          outf[(m0 + r) * N_ + n] = acc[mf][nf][r] + bv;
      }
    }
  }
}

// ---------------- causal flash attention ----------------
// Q,K: [B*H, T, 64] bf16 (Q pre-scaled by 0.125); Vt: [B*H, 64, T] bf16
// Y: [B*T, 1024] bf16.  Block: (qtile, bh), 4 waves x 16 q-rows, KVBLK=64.
__global__ __launch_bounds__(256) void attn_kernel(
    const short* __restrict__ Q, const short* __restrict__ Kg,
    const short* __restrict__ Vt, short* __restrict__ Y){
  __shared__ short Ks[64 * 64];
  __shared__ short Vs[64 * 64];
  __shared__ short Ps[64 * 64];
  const int tid = threadIdx.x, lane = tid & 63, w = tid >> 6;
  const int qt = blockIdx.x, bh = blockIdx.y;
  const int lr = lane & 15, lk = lane >> 4;
  const int q0 = qt * 64 + w * 16;

  const short* qbase = Q + (bh * T_ + q0 + lr) * HD_;
  bf16x8 qa[2];
  qa[0] = *(const bf16x8*)(qbase + lk * 8);
  qa[1] = *(const bf16x8*)(qbase + 32 + lk * 8);

  f32x4 o[4] = {};
  float m[4], l[4];
#pragma unroll
  for (int r = 0; r < 4; r++){ m[r] = -1e30f; l[r] = 0.f; }

  for (int kvt = 0; kvt <= qt; ++kvt){
    // stage K [64 t][64 hd] and V^T [64 hd][64 t], XOR-swizzled via source addr
#pragma unroll
    for (int i = 0; i < 2; i++){
      int idx = i * 256 + tid;
      int row = idx >> 3, cb = (idx & 7) * 16;       // 128B rows
      int cbl = cb ^ ((row & 7) << 4);
      gl2lds16(Kg + (bh * T_ + kvt * 64 + row) * HD_ + (cbl >> 1), (char*)Ks + idx * 16);
      gl2lds16(Vt + (bh * HD_ + row) * T_ + kvt * 64 + (cbl >> 1), (char*)Vs + idx * 16);
    }
    __syncthreads();

    // S = Q K^T  (16 x 64 per wave)
    f32x4 s[4] = {};
#pragma unroll
    for (int nf = 0; nf < 4; nf++){
#pragma unroll
      for (int ks = 0; ks < 2; ks++){
        int row = nf * 16 + lr;
        int cb = ks * 64 + lk * 16;
        bf16x8 kb = *(const bf16x8*)((const char*)Ks + row * 128 + (cb ^ ((row & 7) << 4)));
        s[nf] = __builtin_amdgcn_mfma_f32_16x16x32_bf16(qa[ks], kb, s[nf], 0, 0, 0);
      }
    }

    if (kvt == qt){   // causal mask on diagonal tile
#pragma unroll
      for (int nf = 0; nf < 4; nf++)
#pragma unroll
        for (int r = 0; r < 4; r++)
          if (nf * 16 + lr > w * 16 + lk * 4 + r) s[nf][r] = -1e30f;
    }

    // online softmax (rows live in 16-lane groups)
    float sf_[4];
#pragma unroll
    for (int r = 0; r < 4; r++){
      float v = fmaxf(fmaxf(s[0][r], s[1][r]), fmaxf(s[2][r], s[3][r]));
      v = fmaxf(v, __shfl_xor(v, 1));
      v = fmaxf(v, __shfl_xor(v, 2));
      v = fmaxf(v, __shfl_xor(v, 4));
      v = fmaxf(v, __shfl_xor(v, 8));
      float mn = fmaxf(m[r], v);
      sf_[r] = __expf(m[r] - mn);
      m[r] = mn;
    }
#pragma unroll
    for (int r = 0; r < 4; r++){
      float t = 0.f;
#pragma unroll
      for (int nf = 0; nf < 4; nf++){
        float p = __expf(s[nf][r] - m[r]);
        s[nf][r] = p;
        t += p;
      }
      t += __shfl_xor(t, 1); t += __shfl_xor(t, 2);
      t += __shfl_xor(t, 4); t += __shfl_xor(t, 8);
      l[r] = l[r] * sf_[r] + t;
#pragma unroll
      for (int hdf = 0; hdf < 4; hdf++) o[hdf][r] *= sf_[r];
    }

    // P (bf16) -> LDS (swizzled), wave-private region
#pragma unroll
    for (int nf = 0; nf < 4; nf++)
#pragma unroll
      for (int r = 0; r < 4; r++){
        int row = (w << 4) + (lk << 2) + r;
        int cb = ((nf << 4) + lr) << 1;
        *(short*)((char*)Ps + row * 128 + (cb ^ ((row & 7) << 4))) = f2bf(s[nf][r]);
      }

    // O += P @ V
#pragma unroll
    for (int ks = 0; ks < 2; ks++){
      int prow = (w << 4) + lr;
      int pcb = ks * 64 + lk * 16;
      bf16x8 pa = *(const bf16x8*)((const char*)Ps + prow * 128 + (pcb ^ ((prow & 7) << 4)));
#pragma unroll
      for (int hdf = 0; hdf < 4; hdf++){
        int vrow = hdf * 16 + lr;
        int vcb = ks * 64 + lk * 16;
        bf16x8 vb = *(const bf16x8*)((const char*)Vs + vrow * 128 + (vcb ^ ((vrow & 7) << 4)));
        o[hdf] = __builtin_amdgcn_mfma_f32_16x16x32_bf16(pa, vb, o[hdf], 0, 0, 0);
      }
    }
    __syncthreads();   // all waves done with Ks/Vs before restage
  }

  int b = bh >> 4, h = bh & 15;
#pragma unroll
  for (int hdf = 0; hdf < 4; hdf++)
#pragma unroll
    for (int r = 0; r < 4; r++){
      int t = q0 + lk * 4 + r;
      float val = o[hdf][r] / l[r];
      Y[(b * T_ + t) * D_ + h * 64 + hdf * 16 + lr] = f2bf(val);
    }
}

// ---------------- launch ----------------
extern "C" void kernel_launch(void* const* d_in, const int* in_sizes, int n_in,
                              void* d_out, int out_size, void* d_ws, size_t ws_size,
                              hipStream_t stream) {
  const float* x  = (const float*)d_in[0];
  const float* W1 = (const float*)d_in[1];
  const float* b1 = (const float*)d_in[2];
  const float* W2 = (const float*)d_in[3];
  const float* b2 = (const float*)d_in[4];
  float* out = (float*)d_out;

  char* ws = (char*)d_ws;
  short* W1T = (short*)(ws);                         // [3072][1024] bf16, 6 MB
  short* W2T = (short*)(ws + 6291456);               // [1024][1024] bf16, 2 MB
  short* xb  = (short*)(ws + 8388608);               // [4096][1024] bf16, 8 MB
  short* q   = (short*)(ws + 16777216);              // [B,H,T,64]  bf16, 8 MB
  short* kk  = (short*)(ws + 25165824);              // [B,H,T,64]  bf16, 8 MB
  short* vT  = (short*)(ws + 33554432);              // [B,H,64,T]  bf16, 8 MB
  short* y   = xb;                                   // alias: xb dead after QKV GEMM

  convert_f32_bf16<<<dim3(4096), dim3(256), 0, stream>>>(x, xb);
  transpose_f32_bf16<<<dim3(96, 32), dim3(256), 0, stream>>>(W1, W1T, 1024, 3072);
  transpose_f32_bf16<<<dim3(32, 32), dim3(256), 0, stream>>>(W2, W2T, 1024, 1024);
  gemm_bt<3072, 1024, 0><<<dim3(24, 32), dim3(256), 0, stream>>>(xb, W1T, b1, q, kk, vT, nullptr);
  attn_kernel<<<dim3(32, 32), dim3(256), 0, stream>>>(q, kk, vT, y);
  gemm_bt<1024, 1024, 1><<<dim3(8, 32), dim3(256), 0, stream>>>(y, W2T, b2, nullptr, nullptr, nullptr, out);
}

// Round 2
// 162.732 us; speedup vs baseline: 1.1937x; 1.1937x over previous
//
#include <hip/hip_runtime.h>

typedef __attribute__((ext_vector_type(8))) short bf16x8;
typedef __attribute__((ext_vector_type(4))) float f32x4;
typedef __attribute__((ext_vector_type(4))) short short4v;

#define B_  2
#define T_  2048
#define D_  1024
#define H_  16
#define HD_ 64

__device__ inline short f2bf(float f){
  unsigned u = __builtin_bit_cast(unsigned, f);
  u += 0x7fff + ((u >> 16) & 1);          // round-to-nearest-even
  return (short)(u >> 16);
}

__device__ inline void gl2lds16(const void* g, void* l){
  __builtin_amdgcn_global_load_lds(
      (const __attribute__((address_space(1))) unsigned int*)g,
      (__attribute__((address_space(3))) unsigned int*)l, 16, 0, 0);
}

// ---------------- elementwise f32 -> bf16 ----------------
__global__ __launch_bounds__(256) void convert_f32_bf16(
    const float* __restrict__ in, short* __restrict__ out){
  int i = (blockIdx.x * 256 + threadIdx.x) * 4;
  float4 v = *(const float4*)(in + i);
  short4v o;
  o[0] = f2bf(v.x); o[1] = f2bf(v.y); o[2] = f2bf(v.z); o[3] = f2bf(v.w);
  *(short4v*)(out + i) = o;
}

// ---------------- f32 [R][C] -> bf16 [C][R] ----------------
__global__ __launch_bounds__(256) void transpose_f32_bf16(
    const float* __restrict__ in, short* __restrict__ out, int R, int C){
  __shared__ float tile[32][33];
  int tx = threadIdx.x & 31, ty0 = threadIdx.x >> 5;
  int bx = blockIdx.x << 5, by = blockIdx.y << 5;
#pragma unroll
  for (int i = 0; i < 4; i++){
    int ty = ty0 + i * 8;
    tile[ty][tx] = in[(by + ty) * C + bx + tx];
  }
  __syncthreads();
#pragma unroll
  for (int i = 0; i < 4; i++){
    int ty = ty0 + i * 8;
    out[(bx + ty) * R + by + tx] = f2bf(tile[tx][ty]);
  }
}

// ---------------- GEMM: C = A[M][K] @ Bt[N][K]^T + bias ----------------
#define BM 128
#define BN 128
#define BK 32

template<int N_, int K_, int EPI>
__global__ __launch_bounds__(256) void gemm_bt(
    const short* __restrict__ A, const short* __restrict__ Bt,
    const float* __restrict__ bias,
    short* __restrict__ q, short* __restrict__ kk, short* __restrict__ vT,
    float* __restrict__ outf){
  __shared__ short As[BM * BK];
  __shared__ short Bs[BN * BK];
  const int tid = threadIdx.x;
  const int lane = tid & 63, w = tid >> 6;
  const int wm = w >> 1, wn = w & 1;
  const int lr = lane & 15, lk = lane >> 4;
  const int brow = blockIdx.y * BM, bcol = blockIdx.x * BN;
  f32x4 acc[4][4] = {};
  const short* Ag = A  + brow * K_;
  const short* Bg = Bt + bcol * K_;

  for (int k0 = 0; k0 < K_; k0 += BK){
#pragma unroll
    for (int i = 0; i < 2; i++){
      int idx = i * 256 + tid;
      int row = idx >> 2, c8 = (idx & 3) * 8;   // 64B rows of 32 bf16
      gl2lds16(Ag + row * K_ + k0 + c8, (char*)As + idx * 16);
      gl2lds16(Bg + row * K_ + k0 + c8, (char*)Bs + idx * 16);
    }
    __syncthreads();
    bf16x8 a[4], b[4];
#pragma unroll
    for (int mf = 0; mf < 4; mf++)
      a[mf] = *(const bf16x8*)(As + (wm * 64 + mf * 16 + lr) * BK + lk * 8);
#pragma unroll
    for (int nf = 0; nf < 4; nf++)
      b[nf] = *(const bf16x8*)(Bs + (wn * 64 + nf * 16 + lr) * BK + lk * 8);
#pragma unroll
    for (int mf = 0; mf < 4; mf++)
#pragma unroll
      for (int nf = 0; nf < 4; nf++)
        acc[mf][nf] = __builtin_amdgcn_mfma_f32_16x16x32_bf16(a[mf], b[nf], acc[mf][nf], 0, 0, 0);
    __syncthreads();
  }

  if constexpr (EPI == 0){
    // C/D layout: col = lane&15, row = (lane>>4)*4 + r
#pragma unroll
    for (int nf = 0; nf < 4; nf++){
      int n = bcol + wn * 64 + nf * 16 + lr;
      float bv = bias[n];
      int sec = n >> 10, d = n & 1023, h = d >> 6, hd = d & 63;
#pragma unroll
      for (int mf = 0; mf < 4; mf++){
        int m0 = brow + wm * 64 + mf * 16 + lk * 4;
        int b = m0 >> 11, t0 = m0 & 2047;
        int bh = b * H_ + h;
        if (sec == 0){
#pragma unroll
          for (int r = 0; r < 4; r++)
            q[(bh * T_ + t0 + r) * HD_ + hd] = f2bf((acc[mf][nf][r] + bv) * 0.125f);
        } else if (sec == 1){
#pragma unroll
          for (int r = 0; r < 4; r++)
            kk[(bh * T_ + t0 + r) * HD_ + hd] = f2bf(acc[mf][nf][r] + bv);
        } else {
          float v0 = acc[mf][nf][0] + bv, v1 = acc[mf][nf][1] + bv;
          float v2 = acc[mf][nf][2] + bv, v3 = acc[mf][nf][3] + bv;
          unsigned lo = (unsigned)(unsigned short)f2bf(v0) | ((unsigned)(unsigned short)f2bf(v1) << 16);
          unsigned hi = (unsigned)(unsigned short)f2bf(v2) | ((unsigned)(unsigned short)f2bf(v3) << 16);
          uint2 pk; pk.x = lo; pk.y = hi;
          *(uint2*)(vT + (bh * HD_ + hd) * T_ + t0) = pk;   // v stored transposed [B,H,hd,T]
        }
      }
    }
  } else {
#pragma unroll
    for (int nf = 0; nf < 4; nf++){
      int n = bcol + wn * 64 + nf * 16 + lr;
      float bv = bias[n];
#pragma unroll
      for (int mf = 0; mf < 4; mf++){
        int m0 = brow + wm * 64 + mf * 16 + lk * 4;
#pragma unroll
        for (int r = 0; r < 4; r++)
          outf[(m0 + r) * N_ + n] = acc[mf][nf][r] + bv;
      }
    }
  }
}

// ---------------- causal flash attention ----------------
// Q,K: [B*H, T, 64] bf16 (Q pre-scaled by 0.125); Vt: [B*H, 64, T] bf16
// Y: [B*T, 1024] bf16.
// Pairing: block bx processes q-tiles bx and 31-bx -> uniform 33 kv-steps.
// Double-buffered K/V staging with counted vmcnt (T3/T4 minimal 2-phase).
__global__ __launch_bounds__(256) void attn_kernel(
    const short* __restrict__ Q, const short* __restrict__ Kg,
    const short* __restrict__ Vt, short* __restrict__ Y){
  __shared__ short Ks[2][64 * 64];
  __shared__ short Vs[2][64 * 64];
  __shared__ short Ps[64 * 64];
  const int tid = threadIdx.x, lane = tid & 63, w = tid >> 6;
  const int bh = blockIdx.y;
  const int b = bh >> 4, h = bh & 15;
  const int lr = lane & 15, lk = lane >> 4;

  auto stage = [&](int buf, int kvt){
#pragma unroll
    for (int i = 0; i < 2; i++){
      int idx = i * 256 + tid;
      int row = idx >> 3, cb = (idx & 7) * 16;       // 128B rows
      int cbl = cb ^ ((row & 7) << 4);
      gl2lds16(Kg + (bh * T_ + kvt * 64 + row) * HD_ + (cbl >> 1), (char*)Ks[buf] + idx * 16);
      gl2lds16(Vt + (bh * HD_ + row) * T_ + kvt * 64 + (cbl >> 1), (char*)Vs[buf] + idx * 16);
    }
  };

  auto process = [&](int qt){
    const int q0 = qt * 64 + w * 16;
    const short* qbase = Q + (bh * T_ + q0 + lr) * HD_;
    bf16x8 qa[2];
    qa[0] = *(const bf16x8*)(qbase + lk * 8);
    qa[1] = *(const bf16x8*)(qbase + 32 + lk * 8);

    f32x4 o[4] = {};
    float m[4], l[4];
#pragma unroll
    for (int r = 0; r < 4; r++){ m[r] = -1e30f; l[r] = 0.f; }

    const int nt = qt + 1;
    stage(0, 0);
    for (int t = 0; t < nt; ++t){
      const int cur = t & 1;
      if (t + 1 < nt){
        stage(cur ^ 1, t + 1);                          // prefetch next tile
        asm volatile("s_waitcnt vmcnt(4)" ::: "memory"); // wait current tile only
      } else {
        asm volatile("s_waitcnt vmcnt(0)" ::: "memory");
      }
      __syncthreads();
      const short* Kc = Ks[cur];
      const short* Vc = Vs[cur];

      // S = Q K^T  (16 x 64 per wave)
      f32x4 s[4] = {};
      __builtin_amdgcn_s_setprio(1);
#pragma unroll
      for (int nf = 0; nf < 4; nf++){
#pragma unroll
        for (int ks = 0; ks < 2; ks++){
          int row = nf * 16 + lr;
          int cb = ks * 64 + lk * 16;
          bf16x8 kb = *(const bf16x8*)((const char*)Kc + row * 128 + (cb ^ ((row & 7) << 4)));
          s[nf] = __builtin_amdgcn_mfma_f32_16x16x32_bf16(qa[ks], kb, s[nf], 0, 0, 0);
        }
      }
      __builtin_amdgcn_s_setprio(0);

      if (t == qt){   // causal mask on diagonal tile
#pragma unroll
        for (int nf = 0; nf < 4; nf++)
#pragma unroll
          for (int r = 0; r < 4; r++)
            if (nf * 16 + lr > w * 16 + lk * 4 + r) s[nf][r] = -1e30f;
      }

      // online softmax (rows live in 16-lane groups)
      float sf_[4];
#pragma unroll
      for (int r = 0; r < 4; r++){
        float v = fmaxf(fmaxf(s[0][r], s[1][r]), fmaxf(s[2][r], s[3][r]));
        v = fmaxf(v, __shfl_xor(v, 1));
        v = fmaxf(v, __shfl_xor(v, 2));
        v = fmaxf(v, __shfl_xor(v, 4));
        v = fmaxf(v, __shfl_xor(v, 8));
        float mn = fmaxf(m[r], v);
        sf_[r] = __expf(m[r] - mn);
        m[r] = mn;
      }
#pragma unroll
      for (int r = 0; r < 4; r++){
        float tacc = 0.f;
#pragma unroll
        for (int nf = 0; nf < 4; nf++){
          float p = __expf(s[nf][r] - m[r]);
          s[nf][r] = p;
          tacc += p;
        }
        tacc += __shfl_xor(tacc, 1); tacc += __shfl_xor(tacc, 2);
        tacc += __shfl_xor(tacc, 4); tacc += __shfl_xor(tacc, 8);
        l[r] = l[r] * sf_[r] + tacc;
#pragma unroll
        for (int hdf = 0; hdf < 4; hdf++) o[hdf][r] *= sf_[r];
      }

      // P (bf16) -> LDS (swizzled), wave-private region
#pragma unroll
      for (int nf = 0; nf < 4; nf++)
#pragma unroll
        for (int r = 0; r < 4; r++){
          int row = (w << 4) + (lk << 2) + r;
          int cb = ((nf << 4) + lr) << 1;
          *(short*)((char*)Ps + row * 128 + (cb ^ ((row & 7) << 4))) = f2bf(s[nf][r]);
        }

      // O += P @ V
      __builtin_amdgcn_s_setprio(1);
#pragma unroll
      for (int ks = 0; ks < 2; ks++){
        int prow = (w << 4) + lr;
        int pcb = ks * 64 + lk * 16;
        bf16x8 pa = *(const bf16x8*)((const char*)Ps + prow * 128 + (pcb ^ ((prow & 7) << 4)));
#pragma unroll
        for (int hdf = 0; hdf < 4; hdf++){
          int vrow = hdf * 16 + lr;
          int vcb = ks * 64 + lk * 16;
          bf16x8 vb = *(const bf16x8*)((const char*)Vc + vrow * 128 + (vcb ^ ((vrow & 7) << 4)));
          o[hdf] = __builtin_amdgcn_mfma_f32_16x16x32_bf16(pa, vb, o[hdf], 0, 0, 0);
        }
      }
      __builtin_amdgcn_s_setprio(0);
      __syncthreads();   // all waves done with Ks/Vs[cur] before restaging it
    }

#pragma unroll
    for (int hdf = 0; hdf < 4; hdf++)
#pragma unroll
      for (int r = 0; r < 4; r++){
        int t = q0 + lk * 4 + r;
        float val = o[hdf][r] / l[r];
        Y[(b * T_ + t) * D_ + h * 64 + hdf * 16 + lr] = f2bf(val);
      }
  };

  const int bx = blockIdx.x;
  process(bx);        // light tile: bx+1 kv-steps
  process(31 - bx);   // heavy tile: 32-bx kv-steps  (total 33, uniform)
}

// ---------------- launch ----------------
extern "C" void kernel_launch(void* const* d_in, const int* in_sizes, int n_in,
                              void* d_out, int out_size, void* d_ws, size_t ws_size,
                              hipStream_t stream) {
  const float* x  = (const float*)d_in[0];
  const float* W1 = (const float*)d_in[1];
  const float* b1 = (const float*)d_in[2];
  const float* W2 = (const float*)d_in[3];
  const float* b2 = (const float*)d_in[4];
  float* out = (float*)d_out;

  char* ws = (char*)d_ws;
  short* W1T = (short*)(ws);                         // [3072][1024] bf16, 6 MB
  short* W2T = (short*)(ws + 6291456);               // [1024][1024] bf16, 2 MB
  short* xb  = (short*)(ws + 8388608);               // [4096][1024] bf16, 8 MB
  short* q   = (short*)(ws + 16777216);              // [B,H,T,64]  bf16, 8 MB
  short* kk  = (short*)(ws + 25165824);              // [B,H,T,64]  bf16, 8 MB
  short* vT  = (short*)(ws + 33554432);              // [B,H,64,T]  bf16, 8 MB
  short* y   = xb;                                   // alias: xb dead after QKV GEMM

  convert_f32_bf16<<<dim3(4096), dim3(256), 0, stream>>>(x, xb);
  transpose_f32_bf16<<<dim3(96, 32), dim3(256), 0, stream>>>(W1, W1T, 1024, 3072);
  transpose_f32_bf16<<<dim3(32, 32), dim3(256), 0, stream>>>(W2, W2T, 1024, 1024);
  gemm_bt<3072, 1024, 0><<<dim3(24, 32), dim3(256), 0, stream>>>(xb, W1T, b1, q, kk, vT, nullptr);
  attn_kernel<<<dim3(16, 32), dim3(256), 0, stream>>>(q, kk, vT, y);
  gemm_bt<1024, 1024, 1><<<dim3(8, 32), dim3(256), 0, stream>>>(y, W2T, b2, nullptr, nullptr, nullptr, out);
}

// Round 4
// 140.931 us; speedup vs baseline: 1.3783x; 1.1547x over previous
//
#include <hip/hip_runtime.h>

typedef __attribute__((ext_vector_type(8))) short bf16x8;
typedef __attribute__((ext_vector_type(4))) float f32x4;
typedef __attribute__((ext_vector_type(16))) float f32x16;
typedef __attribute__((ext_vector_type(4))) short short4v;
typedef __attribute__((ext_vector_type(4))) unsigned int uint4v;

#define B_  2
#define T_  2048
#define D_  1024
#define H_  16
#define HD_ 64

__device__ inline short f2bf(float f){
  unsigned u = __builtin_bit_cast(unsigned, f);
  u += 0x7fff + ((u >> 16) & 1);          // round-to-nearest-even
  return (short)(u >> 16);
}

__device__ inline void gl2lds16(const void* g, void* l){
  __builtin_amdgcn_global_load_lds(
      (const __attribute__((address_space(1))) unsigned int*)g,
      (__attribute__((address_space(3))) unsigned int*)l, 16, 0, 0);
}

// ---------------- elementwise f32 -> bf16 ----------------
__global__ __launch_bounds__(256) void convert_f32_bf16(
    const float* __restrict__ in, short* __restrict__ out){
  int i = (blockIdx.x * 256 + threadIdx.x) * 4;
  float4 v = *(const float4*)(in + i);
  short4v o;
  o[0] = f2bf(v.x); o[1] = f2bf(v.y); o[2] = f2bf(v.z); o[3] = f2bf(v.w);
  *(short4v*)(out + i) = o;
}

// ---------------- f32 [R][C] -> bf16 [C][R] ----------------
__global__ __launch_bounds__(256) void transpose_f32_bf16(
    const float* __restrict__ in, short* __restrict__ out, int R, int C){
  __shared__ float tile[32][33];
  int tx = threadIdx.x & 31, ty0 = threadIdx.x >> 5;
  int bx = blockIdx.x << 5, by = blockIdx.y << 5;
#pragma unroll
  for (int i = 0; i < 4; i++){
    int ty = ty0 + i * 8;
    tile[ty][tx] = in[(by + ty) * C + bx + tx];
  }
  __syncthreads();
#pragma unroll
  for (int i = 0; i < 4; i++){
    int ty = ty0 + i * 8;
    out[(bx + ty) * R + by + tx] = f2bf(tile[tx][ty]);
  }
}

// ---------------- GEMM: C = A[M][K] @ Bt[N][K]^T + bias ----------------
#define BM 128
#define BN 128
#define BK 32

// Q pre-scale: 1/sqrt(64) * log2(e)  (softmax runs in exp2 domain)
#define QSCALE 0.18033688011112042f

template<int N_, int K_, int EPI>
__global__ __launch_bounds__(256) void gemm_bt(
    const short* __restrict__ A, const short* __restrict__ Bt,
    const float* __restrict__ bias,
    short* __restrict__ q, short* __restrict__ kk, short* __restrict__ vT,
    float* __restrict__ outf){
  __shared__ short As[BM * BK];
  __shared__ short Bs[BN * BK];
  const int tid = threadIdx.x;
  const int lane = tid & 63, w = tid >> 6;
  const int wm = w >> 1, wn = w & 1;
  const int lr = lane & 15, lk = lane >> 4;
  const int brow = blockIdx.y * BM, bcol = blockIdx.x * BN;
  f32x4 acc[4][4] = {};
  const short* Ag = A  + brow * K_;
  const short* Bg = Bt + bcol * K_;

  for (int k0 = 0; k0 < K_; k0 += BK){
#pragma unroll
    for (int i = 0; i < 2; i++){
      int idx = i * 256 + tid;
      int row = idx >> 2, c8 = (idx & 3) * 8;   // 64B rows of 32 bf16
      gl2lds16(Ag + row * K_ + k0 + c8, (char*)As + idx * 16);
      gl2lds16(Bg + row * K_ + k0 + c8, (char*)Bs + idx * 16);
    }
    __syncthreads();
    bf16x8 a[4], b[4];
#pragma unroll
    for (int mf = 0; mf < 4; mf++)
      a[mf] = *(const bf16x8*)(As + (wm * 64 + mf * 16 + lr) * BK + lk * 8);
#pragma unroll
    for (int nf = 0; nf < 4; nf++)
      b[nf] = *(const bf16x8*)(Bs + (wn * 64 + nf * 16 + lr) * BK + lk * 8);
#pragma unroll
    for (int mf = 0; mf < 4; mf++)
#pragma unroll
      for (int nf = 0; nf < 4; nf++)
        acc[mf][nf] = __builtin_amdgcn_mfma_f32_16x16x32_bf16(a[mf], b[nf], acc[mf][nf], 0, 0, 0);
    __syncthreads();
  }

  if constexpr (EPI == 0){
    // C/D layout: col = lane&15, row = (lane>>4)*4 + r
#pragma unroll
    for (int nf = 0; nf < 4; nf++){
      int n = bcol + wn * 64 + nf * 16 + lr;
      float bv = bias[n];
      int sec = n >> 10, d = n & 1023, h = d >> 6, hd = d & 63;
#pragma unroll
      for (int mf = 0; mf < 4; mf++){
        int m0 = brow + wm * 64 + mf * 16 + lk * 4;
        int b = m0 >> 11, t0 = m0 & 2047;
        int bh = b * H_ + h;
        if (sec == 0){
#pragma unroll
          for (int r = 0; r < 4; r++)
            q[(bh * T_ + t0 + r) * HD_ + hd] = f2bf((acc[mf][nf][r] + bv) * QSCALE);
        } else if (sec == 1){
#pragma unroll
          for (int r = 0; r < 4; r++)
            kk[(bh * T_ + t0 + r) * HD_ + hd] = f2bf(acc[mf][nf][r] + bv);
        } else {
          float v0 = acc[mf][nf][0] + bv, v1 = acc[mf][nf][1] + bv;
          float v2 = acc[mf][nf][2] + bv, v3 = acc[mf][nf][3] + bv;
          unsigned lo = (unsigned)(unsigned short)f2bf(v0) | ((unsigned)(unsigned short)f2bf(v1) << 16);
          unsigned hi = (unsigned)(unsigned short)f2bf(v2) | ((unsigned)(unsigned short)f2bf(v3) << 16);
          uint2 pk; pk.x = lo; pk.y = hi;
          *(uint2*)(vT + (bh * HD_ + hd) * T_ + t0) = pk;   // v stored transposed [B,H,hd,T]
        }
      }
    }
  } else {
#pragma unroll
    for (int nf = 0; nf < 4; nf++){
      int n = bcol + wn * 64 + nf * 16 + lr;
      float bv = bias[n];
#pragma unroll
      for (int mf = 0; mf < 4; mf++){
        int m0 = brow + wm * 64 + mf * 16 + lk * 4;
#pragma unroll
        for (int r = 0; r < 4; r++)
          outf[(m0 + r) * N_ + n] = acc[mf][nf][r] + bv;
      }
    }
  }
}

// ---------------- causal flash attention, 32x32 swapped-QK^T ----------------
// Q,K: [B*H, T, 64] bf16 (Q pre-scaled by QSCALE => logits in exp2 domain)
// Vt: [B*H, 64, T] bf16;  Y: [B*T, 1024] bf16.
// Grid: 512 blocks x 4 waves. Block bx -> q-tile i (128 rows), bh = bx&31.
// Ordering: blocks c and c+256 (same CU under nested round-robin) get tile
// sizes summing to a constant -> uniform ~34 kv-steps per CU.
// Each warp owns 32 q-rows. S^T = mfma(K, Q): lane holds a full q-row's kv
// scores -> lane-local softmax. P->PV A-frags via cvt_pk + permlane32_swap
// (D=even, S=odd: D_hi <-> S_lo exchange gives word0=new D, word2=new S).
__global__ __launch_bounds__(256) void attn32(
    const short* __restrict__ Q, const short* __restrict__ Kg,
    const short* __restrict__ Vt, short* __restrict__ Y){
  __shared__ short Ks[2][64 * 64];
  __shared__ short Vs[2][64 * 64];
  __shared__ float bounce[4][32];
  const int tid = threadIdx.x;
  const int w = tid >> 6, l = tid & 63;
  const int lq = l & 31, h = l >> 5;
  const int bx = blockIdx.x;
  const int i = (bx < 256) ? 15 - (bx >> 5) : (bx >> 5) - 8;
  const int bh = bx & 31;
  const int q0 = i * 128, qw = q0 + w * 32;
  const int nt = 2 * (i + 1);

  // Q fragments (B-operand): qb[dk] = Q[qw+lq][16*dk + 8*h .. +7]
  bf16x8 qb[4];
  {
    const short* qbase = Q + (bh * T_ + qw + lq) * HD_;
#pragma unroll
    for (int dk = 0; dk < 4; dk++)
      qb[dk] = *(const bf16x8*)(qbase + dk * 16 + h * 8);
  }

  f32x16 o0 = {}, o1 = {};
  float m = -1e30f, ll = 0.f;

  auto stage = [&](int buf, int t){
#pragma unroll
    for (int j = 0; j < 2; j++){
      int idx = j * 256 + tid;
      int row = idx >> 3, cb = (idx & 7) * 16;     // 128B rows
      int cbs = cb ^ ((row & 7) << 4);
      gl2lds16(Kg + (bh * T_ + t * 64 + row) * HD_ + (cbs >> 1), (char*)Ks[buf] + idx * 16);
      gl2lds16(Vt + (bh * HD_ + row) * T_ + t * 64 + (cbs >> 1), (char*)Vs[buf] + idx * 16);
    }
  };

  stage(0, 0);
  for (int t = 0; t < nt; ++t){
    const int cur = t & 1;
    if (t + 1 < nt){
      stage(cur ^ 1, t + 1);
      asm volatile("s_waitcnt vmcnt(4)" ::: "memory");
    } else {
      asm volatile("s_waitcnt vmcnt(0)" ::: "memory");
    }
    __syncthreads();

    const int kvb = t * 64;
    if (kvb <= qw + 31){                  // warp still below/on its diagonal
      const short* Kc = Ks[cur];
      const short* Vc = Vs[cur];

      // S^T = K . Q^T : s[kb] covers kv [kvb+32*kb, +32), q col = lq
      f32x16 s[2] = {};
      __builtin_amdgcn_s_setprio(1);
#pragma unroll
      for (int kb = 0; kb < 2; kb++){
        int row = kb * 32 + lq;
        const char* rp = (const char*)Kc + row * 128;
        int swz = (row & 7) << 4;
#pragma unroll
        for (int dk = 0; dk < 4; dk++){
          bf16x8 ka = *(const bf16x8*)(rp + ((dk * 32 + h * 16) ^ swz));
          s[kb] = __builtin_amdgcn_mfma_f32_32x32x16_bf16(ka, qb[dk], s[kb], 0, 0, 0);
        }
      }
      __builtin_amdgcn_s_setprio(0);

      const int qg = qw + lq;
      if (kvb + 63 > qw){                 // diagonal tile: causal mask
#pragma unroll
        for (int kb = 0; kb < 2; kb++)
#pragma unroll
          for (int r = 0; r < 16; r++){
            int kv = kvb + kb * 32 + (r & 3) + 8 * (r >> 2) + 4 * h;
            if (kv > qg) s[kb][r] = -1e30f;
          }
      }

      // row max: lane-local + 1 cross-half shuffle
      float pm = s[0][0];
#pragma unroll
      for (int r = 1; r < 16; r++) pm = fmaxf(pm, s[0][r]);
#pragma unroll
      for (int r = 0; r < 16; r++) pm = fmaxf(pm, s[1][r]);
      pm = fmaxf(pm, __shfl_xor(pm, 32));

      // defer-max (T13): rescale O only when max grew > 8 (log2 domain)
      if (__any(pm > m + 8.f)){
        float mn = fmaxf(pm, m);
        float sf = __builtin_amdgcn_exp2f(m - mn);
        m = mn;
        ll *= sf;
        bounce[w][lq] = sf;               // lanes l and l+32 write same value
#pragma unroll
        for (int r = 0; r < 16; r++){
          float sr = bounce[w][(r & 3) + 8 * (r >> 2) + 4 * h];
          o0[r] *= sr; o1[r] *= sr;
        }
      }

      // P = 2^(s - m); row sum
      float ts = 0.f;
#pragma unroll
      for (int kb = 0; kb < 2; kb++)
#pragma unroll
        for (int r = 0; r < 16; r++){
          float p = __builtin_amdgcn_exp2f(s[kb][r] - m);
          s[kb][r] = p;
          ts += p;
        }
      ts += __shfl_xor(ts, 32);
      ll += ts;

      // pack P to bf16 pairs; pw0[kb*4+g] = kv kb*32+8g+4h'+{0,1}, pw1: +{2,3}
      unsigned pw0[8], pw1[8];
#pragma unroll
      for (int kb = 0; kb < 2; kb++)
#pragma unroll
        for (int gg = 0; gg < 4; gg++){
          unsigned r0, r1;
          asm("v_cvt_pk_bf16_f32 %0, %1, %2" : "=v"(r0) : "v"(s[kb][gg * 4 + 0]), "v"(s[kb][gg * 4 + 1]));
          asm("v_cvt_pk_bf16_f32 %0, %1, %2" : "=v"(r1) : "v"(s[kb][gg * 4 + 2]), "v"(s[kb][gg * 4 + 3]));
          pw0[kb * 4 + gg] = r0;
          pw1[kb * 4 + gg] = r1;
        }
      // swap(D=even, S=odd): D_hi <-> S_lo.  After: even reg = A-word0
      // (lo: own-lo value, hi: odd-reg's lo value); odd reg = A-word2.
#pragma unroll
      for (int ks = 0; ks < 4; ks++){
        asm("v_permlane32_swap_b32 %0, %1" : "+v"(pw0[2 * ks]), "+v"(pw0[2 * ks + 1]));
        asm("v_permlane32_swap_b32 %0, %1" : "+v"(pw1[2 * ks]), "+v"(pw1[2 * ks + 1]));
      }

      // O += P @ V
      __builtin_amdgcn_s_setprio(1);
#pragma unroll
      for (int ks = 0; ks < 4; ks++){
        uint4v paw;
        paw[0] = pw0[2 * ks];     paw[1] = pw1[2 * ks];
        paw[2] = pw0[2 * ks + 1]; paw[3] = pw1[2 * ks + 1];
        bf16x8 pa = __builtin_bit_cast(bf16x8, paw);
#pragma unroll
        for (int nb = 0; nb < 2; nb++){
          int row = nb * 32 + lq;
          bf16x8 vb = *(const bf16x8*)((const char*)Vc + row * 128 +
                        ((ks * 32 + h * 16) ^ ((row & 7) << 4)));
          if (nb == 0) o0 = __builtin_amdgcn_mfma_f32_32x32x16_bf16(pa, vb, o0, 0, 0, 0);
          else         o1 = __builtin_amdgcn_mfma_f32_32x32x16_bf16(pa, vb, o1, 0, 0, 0);
        }
      }
      __builtin_amdgcn_s_setprio(0);
    }
    __syncthreads();
  }

  // epilogue: normalize by 1/l (broadcast via warp-private LDS) and store
  bounce[w][lq] = __builtin_amdgcn_rcpf(ll);
  const int b = bh >> 4, hh = bh & 15;
#pragma unroll
  for (int r = 0; r < 16; r++){
    int row = (r & 3) + 8 * (r >> 2) + 4 * h;
    float rl = bounce[w][row];
    int qg = qw + row;
    short* yb = Y + (b * T_ + qg) * D_ + hh * 64;
    yb[lq]      = f2bf(o0[r] * rl);
    yb[32 + lq] = f2bf(o1[r] * rl);
  }
}

// ---------------- launch ----------------
extern "C" void kernel_launch(void* const* d_in, const int* in_sizes, int n_in,
                              void* d_out, int out_size, void* d_ws, size_t ws_size,
                              hipStream_t stream) {
  const float* x  = (const float*)d_in[0];
  const float* W1 = (const float*)d_in[1];
  const float* b1 = (const float*)d_in[2];
  const float* W2 = (const float*)d_in[3];
  const float* b2 = (const float*)d_in[4];
  float* out = (float*)d_out;

  char* ws = (char*)d_ws;
  short* W1T = (short*)(ws);                         // [3072][1024] bf16, 6 MB
  short* W2T = (short*)(ws + 6291456);               // [1024][1024] bf16, 2 MB
  short* xb  = (short*)(ws + 8388608);               // [4096][1024] bf16, 8 MB
  short* q   = (short*)(ws + 16777216);              // [B,H,T,64]  bf16, 8 MB
  short* kk  = (short*)(ws + 25165824);              // [B,H,T,64]  bf16, 8 MB
  short* vT  = (short*)(ws + 33554432);              // [B,H,64,T]  bf16, 8 MB
  short* y   = xb;                                   // alias: xb dead after QKV GEMM

  convert_f32_bf16<<<dim3(4096), dim3(256), 0, stream>>>(x, xb);
  transpose_f32_bf16<<<dim3(96, 32), dim3(256), 0, stream>>>(W1, W1T, 1024, 3072);
  transpose_f32_bf16<<<dim3(32, 32), dim3(256), 0, stream>>>(W2, W2T, 1024, 1024);
  gemm_bt<3072, 1024, 0><<<dim3(24, 32), dim3(256), 0, stream>>>(xb, W1T, b1, q, kk, vT, nullptr);
  attn32<<<dim3(512), dim3(256), 0, stream>>>(q, kk, vT, y);
  gemm_bt<1024, 1024, 1><<<dim3(8, 32), dim3(256), 0, stream>>>(y, W2T, b2, nullptr, nullptr, nullptr, out);
}

// Round 5
// 130.287 us; speedup vs baseline: 1.4909x; 1.0817x over previous
//
#include <hip/hip_runtime.h>

typedef __attribute__((ext_vector_type(8))) short bf16x8;
typedef __attribute__((ext_vector_type(4))) float f32x4;
typedef __attribute__((ext_vector_type(16))) float f32x16;
typedef __attribute__((ext_vector_type(4))) short short4v;
typedef __attribute__((ext_vector_type(4))) unsigned int uint4v;

#define B_  2
#define T_  2048
#define D_  1024
#define H_  16
#define HD_ 64

__device__ inline short f2bf(float f){
  unsigned u = __builtin_bit_cast(unsigned, f);
  u += 0x7fff + ((u >> 16) & 1);          // round-to-nearest-even
  return (short)(u >> 16);
}

__device__ inline void gl2lds16(const void* g, void* l){
  __builtin_amdgcn_global_load_lds(
      (const __attribute__((address_space(1))) unsigned int*)g,
      (__attribute__((address_space(3))) unsigned int*)l, 16, 0, 0);
}

// ---------------- elementwise f32 -> bf16 ----------------
__global__ __launch_bounds__(256) void convert_f32_bf16(
    const float* __restrict__ in, short* __restrict__ out){
  int i = (blockIdx.x * 256 + threadIdx.x) * 4;
  float4 v = *(const float4*)(in + i);
  short4v o;
  o[0] = f2bf(v.x); o[1] = f2bf(v.y); o[2] = f2bf(v.z); o[3] = f2bf(v.w);
  *(short4v*)(out + i) = o;
}

// ---------------- f32 [R][C] -> bf16 [C][R] ----------------
__global__ __launch_bounds__(256) void transpose_f32_bf16(
    const float* __restrict__ in, short* __restrict__ out, int R, int C){
  __shared__ float tile[32][33];
  int tx = threadIdx.x & 31, ty0 = threadIdx.x >> 5;
  int bx = blockIdx.x << 5, by = blockIdx.y << 5;
#pragma unroll
  for (int i = 0; i < 4; i++){
    int ty = ty0 + i * 8;
    tile[ty][tx] = in[(by + ty) * C + bx + tx];
  }
  __syncthreads();
#pragma unroll
  for (int i = 0; i < 4; i++){
    int ty = ty0 + i * 8;
    out[(bx + ty) * R + by + tx] = f2bf(tile[tx][ty]);
  }
}

// ---------------- GEMM: C = A[M][K] @ Bt[N][K]^T + bias ----------------
// 2-phase double-buffered pipeline, raw barriers, counted vmcnt (T3+T4).
#define BM 128
#define BN 128
#define BK 32

// Q pre-scale: 1/sqrt(64) * log2(e)  (softmax runs in exp2 domain)
#define QSCALE 0.18033688011112042f

template<int N_, int K_, int EPI>
__global__ __launch_bounds__(256) void gemm_bt(
    const short* __restrict__ A, const short* __restrict__ Bt,
    const float* __restrict__ bias,
    short* __restrict__ q, short* __restrict__ kk, short* __restrict__ vT,
    float* __restrict__ outf){
  __shared__ short As[2][BM * BK];
  __shared__ short Bs[2][BN * BK];
  const int tid = threadIdx.x;
  const int lane = tid & 63, w = tid >> 6;
  const int wm = w >> 1, wn = w & 1;
  const int lr = lane & 15, lk = lane >> 4;
  const int brow = blockIdx.y * BM, bcol = blockIdx.x * BN;
  f32x4 acc[4][4] = {};
  const short* Ag = A  + brow * K_;
  const short* Bg = Bt + bcol * K_;

  auto stage = [&](int buf, int k0){
#pragma unroll
    for (int i = 0; i < 2; i++){
      int idx = i * 256 + tid;
      int row = idx >> 2, c8 = (idx & 3) * 8;   // 64B rows of 32 bf16
      gl2lds16(Ag + row * K_ + k0 + c8, (char*)As[buf] + idx * 16);
      gl2lds16(Bg + row * K_ + k0 + c8, (char*)Bs[buf] + idx * 16);
    }
  };

  const int NT = K_ / BK;
  stage(0, 0);
  for (int t = 0; t < NT; ++t){
    const int cur = t & 1;
    if (t + 1 < NT){
      stage(cur ^ 1, (t + 1) * BK);                    // prefetch next K-tile
      asm volatile("s_waitcnt vmcnt(4)" ::: "memory"); // current tile landed
    } else {
      asm volatile("s_waitcnt vmcnt(0)" ::: "memory");
    }
    __builtin_amdgcn_s_barrier();                      // buf[cur] fully staged
    __builtin_amdgcn_sched_barrier(0);

    bf16x8 a[4], b[4];
#pragma unroll
    for (int mf = 0; mf < 4; mf++)
      a[mf] = *(const bf16x8*)(As[cur] + (wm * 64 + mf * 16 + lr) * BK + lk * 8);
#pragma unroll
    for (int nf = 0; nf < 4; nf++)
      b[nf] = *(const bf16x8*)(Bs[cur] + (wn * 64 + nf * 16 + lr) * BK + lk * 8);
    __builtin_amdgcn_s_setprio(1);
#pragma unroll
    for (int mf = 0; mf < 4; mf++)
#pragma unroll
      for (int nf = 0; nf < 4; nf++)
        acc[mf][nf] = __builtin_amdgcn_mfma_f32_16x16x32_bf16(a[mf], b[nf], acc[mf][nf], 0, 0, 0);
    __builtin_amdgcn_s_setprio(0);
    __builtin_amdgcn_sched_barrier(0);
    __builtin_amdgcn_s_barrier();                      // reads of buf[cur] done
  }

  if constexpr (EPI == 0){
    // C/D layout: col = lane&15, row = (lane>>4)*4 + r
#pragma unroll
    for (int nf = 0; nf < 4; nf++){
      int n = bcol + wn * 64 + nf * 16 + lr;
      float bv = bias[n];
      int sec = n >> 10, d = n & 1023, h = d >> 6, hd = d & 63;
#pragma unroll
      for (int mf = 0; mf < 4; mf++){
        int m0 = brow + wm * 64 + mf * 16 + lk * 4;
        int b = m0 >> 11, t0 = m0 & 2047;
        int bh = b * H_ + h;
        if (sec == 0){
#pragma unroll
          for (int r = 0; r < 4; r++)
            q[(bh * T_ + t0 + r) * HD_ + hd] = f2bf((acc[mf][nf][r] + bv) * QSCALE);
        } else if (sec == 1){
#pragma unroll
          for (int r = 0; r < 4; r++)
            kk[(bh * T_ + t0 + r) * HD_ + hd] = f2bf(acc[mf][nf][r] + bv);
        } else {
          float v0 = acc[mf][nf][0] + bv, v1 = acc[mf][nf][1] + bv;
          float v2 = acc[mf][nf][2] + bv, v3 = acc[mf][nf][3] + bv;
          unsigned lo = (unsigned)(unsigned short)f2bf(v0) | ((unsigned)(unsigned short)f2bf(v1) << 16);
          unsigned hi = (unsigned)(unsigned short)f2bf(v2) | ((unsigned)(unsigned short)f2bf(v3) << 16);
          uint2 pk; pk.x = lo; pk.y = hi;
          *(uint2*)(vT + (bh * HD_ + hd) * T_ + t0) = pk;   // v stored transposed [B,H,hd,T]
        }
      }
    }
  } else {
#pragma unroll
    for (int nf = 0; nf < 4; nf++){
      int n = bcol + wn * 64 + nf * 16 + lr;
      float bv = bias[n];
#pragma unroll
      for (int mf = 0; mf < 4; mf++){
        int m0 = brow + wm * 64 + mf * 16 + lk * 4;
#pragma unroll
        for (int r = 0; r < 4; r++)
          outf[(m0 + r) * N_ + n] = acc[mf][nf][r] + bv;
      }
    }
  }
}

// ---------------- causal flash attention, 32x32 swapped-QK^T ----------------
// Q,K: [B*H, T, 64] bf16 (Q pre-scaled by QSCALE => logits in exp2 domain)
// Vt: [B*H, 64, T] bf16;  Y: [B*T, 1024] bf16.
// Grid: 512 blocks x 4 waves. Block bx -> q-tile i (128 rows), bh = bx&31.
// Blocks c and c+256 get tile sizes summing constant -> uniform CU load.
// Raw barriers + counted vmcnt: next K/V tile's loads stay in flight
// across the compute phase (true T4 overlap).
__global__ __launch_bounds__(256) void attn32(
    const short* __restrict__ Q, const short* __restrict__ Kg,
    const short* __restrict__ Vt, short* __restrict__ Y){
  __shared__ short Ks[2][64 * 64];
  __shared__ short Vs[2][64 * 64];
  __shared__ float bounce[4][32];
  const int tid = threadIdx.x;
  const int w = tid >> 6, l = tid & 63;
  const int lq = l & 31, h = l >> 5;
  const int bx = blockIdx.x;
  const int i = (bx < 256) ? 15 - (bx >> 5) : (bx >> 5) - 8;
  const int bh = bx & 31;
  const int q0 = i * 128, qw = q0 + w * 32;
  const int nt = 2 * (i + 1);

  // Q fragments (B-operand): qb[dk] = Q[qw+lq][16*dk + 8*h .. +7]
  bf16x8 qb[4];
  {
    const short* qbase = Q + (bh * T_ + qw + lq) * HD_;
#pragma unroll
    for (int dk = 0; dk < 4; dk++)
      qb[dk] = *(const bf16x8*)(qbase + dk * 16 + h * 8);
  }

  f32x16 o0 = {}, o1 = {};
  float m = -1e30f, ll = 0.f;

  auto stage = [&](int buf, int t){
#pragma unroll
    for (int j = 0; j < 2; j++){
      int idx = j * 256 + tid;
      int row = idx >> 3, cb = (idx & 7) * 16;     // 128B rows
      int cbs = cb ^ ((row & 7) << 4);
      gl2lds16(Kg + (bh * T_ + t * 64 + row) * HD_ + (cbs >> 1), (char*)Ks[buf] + idx * 16);
      gl2lds16(Vt + (bh * HD_ + row) * T_ + t * 64 + (cbs >> 1), (char*)Vs[buf] + idx * 16);
    }
  };

  stage(0, 0);
  for (int t = 0; t < nt; ++t){
    const int cur = t & 1;
    if (t + 1 < nt){
      stage(cur ^ 1, t + 1);                            // prefetch next tile
      asm volatile("s_waitcnt vmcnt(4)" ::: "memory");  // current tile landed
    } else {
      asm volatile("s_waitcnt vmcnt(0)" ::: "memory");
    }
    __builtin_amdgcn_s_barrier();
    __builtin_amdgcn_sched_barrier(0);

    const int kvb = t * 64;
    if (kvb <= qw + 31){                  // warp still below/on its diagonal
      const short* Kc = Ks[cur];
      const short* Vc = Vs[cur];

      // S^T = K . Q^T : s[kb] covers kv [kvb+32*kb, +32), q col = lq
      f32x16 s[2] = {};
      __builtin_amdgcn_s_setprio(1);
#pragma unroll
      for (int kb = 0; kb < 2; kb++){
        int row = kb * 32 + lq;
        const char* rp = (const char*)Kc + row * 128;
        int swz = (row & 7) << 4;
#pragma unroll
        for (int dk = 0; dk < 4; dk++){
          bf16x8 ka = *(const bf16x8*)(rp + ((dk * 32 + h * 16) ^ swz));
          s[kb] = __builtin_amdgcn_mfma_f32_32x32x16_bf16(ka, qb[dk], s[kb], 0, 0, 0);
        }
      }
      __builtin_amdgcn_s_setprio(0);

      const int qg = qw + lq;
      if (kvb + 63 > qw){                 // diagonal tile: causal mask
#pragma unroll
        for (int kb = 0; kb < 2; kb++)
#pragma unroll
          for (int r = 0; r < 16; r++){
            int kv = kvb + kb * 32 + (r & 3) + 8 * (r >> 2) + 4 * h;
            if (kv > qg) s[kb][r] = -1e30f;
          }
      }

      // row max: lane-local + 1 cross-half shuffle
      float pm = s[0][0];
#pragma unroll
      for (int r = 1; r < 16; r++) pm = fmaxf(pm, s[0][r]);
#pragma unroll
      for (int r = 0; r < 16; r++) pm = fmaxf(pm, s[1][r]);
      pm = fmaxf(pm, __shfl_xor(pm, 32));

      // defer-max (T13): rescale O only when max grew > 8 (log2 domain)
      if (__any(pm > m + 8.f)){
        float mn = fmaxf(pm, m);
        float sf = __builtin_amdgcn_exp2f(m - mn);
        m = mn;
        ll *= sf;
        bounce[w][lq] = sf;               // lanes l and l+32 write same value
#pragma unroll
        for (int r = 0; r < 16; r++){
          float sr = bounce[w][(r & 3) + 8 * (r >> 2) + 4 * h];
          o0[r] *= sr; o1[r] *= sr;
        }
      }

      // P = 2^(s - m); row sum
      float ts = 0.f;
#pragma unroll
      for (int kb = 0; kb < 2; kb++)
#pragma unroll
        for (int r = 0; r < 16; r++){
          float p = __builtin_amdgcn_exp2f(s[kb][r] - m);
          s[kb][r] = p;
          ts += p;
        }
      ts += __shfl_xor(ts, 32);
      ll += ts;

      // pack P to bf16 pairs; pw0[kb*4+g] = kv kb*32+8g+4h'+{0,1}, pw1: +{2,3}
      unsigned pw0[8], pw1[8];
#pragma unroll
      for (int kb = 0; kb < 2; kb++)
#pragma unroll
        for (int gg = 0; gg < 4; gg++){
          unsigned r0, r1;
          asm("v_cvt_pk_bf16_f32 %0, %1, %2" : "=v"(r0) : "v"(s[kb][gg * 4 + 0]), "v"(s[kb][gg * 4 + 1]));
          asm("v_cvt_pk_bf16_f32 %0, %1, %2" : "=v"(r1) : "v"(s[kb][gg * 4 + 2]), "v"(s[kb][gg * 4 + 3]));
          pw0[kb * 4 + gg] = r0;
          pw1[kb * 4 + gg] = r1;
        }
      // swap(D=even, S=odd): D_hi <-> S_lo.  After: even reg = A-word0
      // (lo: own-lo value, hi: odd-reg's lo value); odd reg = A-word2.
#pragma unroll
      for (int ks = 0; ks < 4; ks++){
        asm("v_permlane32_swap_b32 %0, %1" : "+v"(pw0[2 * ks]), "+v"(pw0[2 * ks + 1]));
        asm("v_permlane32_swap_b32 %0, %1" : "+v"(pw1[2 * ks]), "+v"(pw1[2 * ks + 1]));
      }

      // O += P @ V
      __builtin_amdgcn_s_setprio(1);
#pragma unroll
      for (int ks = 0; ks < 4; ks++){
        uint4v paw;
        paw[0] = pw0[2 * ks];     paw[1] = pw1[2 * ks];
        paw[2] = pw0[2 * ks + 1]; paw[3] = pw1[2 * ks + 1];
        bf16x8 pa = __builtin_bit_cast(bf16x8, paw);
#pragma unroll
        for (int nb = 0; nb < 2; nb++){
          int row = nb * 32 + lq;
          bf16x8 vb = *(const bf16x8*)((const char*)Vc + row * 128 +
                        ((ks * 32 + h * 16) ^ ((row & 7) << 4)));
          if (nb == 0) o0 = __builtin_amdgcn_mfma_f32_32x32x16_bf16(pa, vb, o0, 0, 0, 0);
          else         o1 = __builtin_amdgcn_mfma_f32_32x32x16_bf16(pa, vb, o1, 0, 0, 0);
        }
      }
      __builtin_amdgcn_s_setprio(0);
    }
    __builtin_amdgcn_sched_barrier(0);
    __builtin_amdgcn_s_barrier();        // all reads of buf[cur] done
  }

  // epilogue: normalize by 1/l (broadcast via warp-private LDS) and store
  bounce[w][lq] = __builtin_amdgcn_rcpf(ll);
  const int b = bh >> 4, hh = bh & 15;
#pragma unroll
  for (int r = 0; r < 16; r++){
    int row = (r & 3) + 8 * (r >> 2) + 4 * h;
    float rl = bounce[w][row];
    int qg = qw + row;
    short* yb = Y + (b * T_ + qg) * D_ + hh * 64;
    yb[lq]      = f2bf(o0[r] * rl);
    yb[32 + lq] = f2bf(o1[r] * rl);
  }
}

// ---------------- launch ----------------
extern "C" void kernel_launch(void* const* d_in, const int* in_sizes, int n_in,
                              void* d_out, int out_size, void* d_ws, size_t ws_size,
                              hipStream_t stream) {
  const float* x  = (const float*)d_in[0];
  const float* W1 = (const float*)d_in[1];
  const float* b1 = (const float*)d_in[2];
  const float* W2 = (const float*)d_in[3];
  const float* b2 = (const float*)d_in[4];
  float* out = (float*)d_out;

  char* ws = (char*)d_ws;
  short* W1T = (short*)(ws);                         // [3072][1024] bf16, 6 MB
  short* W2T = (short*)(ws + 6291456);               // [1024][1024] bf16, 2 MB
  short* xb  = (short*)(ws + 8388608);               // [4096][1024] bf16, 8 MB
  short* q   = (short*)(ws + 16777216);              // [B,H,T,64]  bf16, 8 MB
  short* kk  = (short*)(ws + 25165824);              // [B,H,T,64]  bf16, 8 MB
  short* vT  = (short*)(ws + 33554432);              // [B,H,64,T]  bf16, 8 MB
  short* y   = xb;                                   // alias: xb dead after QKV GEMM

  convert_f32_bf16<<<dim3(4096), dim3(256), 0, stream>>>(x, xb);
  transpose_f32_bf16<<<dim3(96, 32), dim3(256), 0, stream>>>(W1, W1T, 1024, 3072);
  transpose_f32_bf16<<<dim3(32, 32), dim3(256), 0, stream>>>(W2, W2T, 1024, 1024);
  gemm_bt<3072, 1024, 0><<<dim3(24, 32), dim3(256), 0, stream>>>(xb, W1T, b1, q, kk, vT, nullptr);
  attn32<<<dim3(512), dim3(256), 0, stream>>>(q, kk, vT, y);
  gemm_bt<1024, 1024, 1><<<dim3(8, 32), dim3(256), 0, stream>>>(y, W2T, b2, nullptr, nullptr, nullptr, out);
}